// Round 6
// baseline (44.599 us; speedup 1.0000x reference)
//
#include <hip/hip_runtime.h>
#include <hip/hip_bf16.h>

typedef __attribute__((ext_vector_type(8))) short s16x8;
typedef __attribute__((ext_vector_type(4))) short s16x4;
typedef __attribute__((ext_vector_type(4))) float fx4;

#define DEVINL __device__ __forceinline__

constexpr int EMBED = 768;
constexpr int HD    = 64;
constexpr int NB    = 16;
constexpr int LEN   = 1024;
constexpr int M_TOT = NB * LEN;   // 16384
constexpr int KVQ   = LEN / 4;    // 256 kv per group in fused attn
constexpr int WELEM = HD * EMBED; // 49152

// fp32 -> bf16 RNE via v_cvt_pk_bf16_f32 (2 elems/inst).
DEVINL unsigned pk2(float lo, float hi) {
  __hip_bfloat162 h = __float22bfloat162_rn(float2{lo, hi});
  union { __hip_bfloat162 h; unsigned u; } c; c.h = h;
  return c.u;
}
DEVINL s16x8 cvt8(fx4 a, fx4 b) {
  union { unsigned u[4]; s16x8 v; } r;
  r.u[0] = pk2(a[0], a[1]); r.u[1] = pk2(a[2], a[3]);
  r.u[2] = pk2(b[0], b[1]); r.u[3] = pk2(b[2], b[3]);
  return r.v;
}
DEVINL s16x4 cvt4(float a0, float a1, float a2, float a3) {
  union { unsigned u[2]; s16x4 v; } r;
  r.u[0] = pk2(a0, a1); r.u[1] = pk2(a2, a3);
  return r.v;
}

DEVINL fx4 mfma16(s16x8 a, s16x8 b, fx4 c) {
  return __builtin_amdgcn_mfma_f32_16x16x32_bf16(a, b, c, 0, 0, 0);
}

// ---------------------------------------------------------------------------
// One-shot: convert Wq|Wk|Wv (each 64x768 fp32) to bf16, packed [3][49152].
// ---------------------------------------------------------------------------
__global__ __launch_bounds__(256) void convert_w_kernel(
    const float* __restrict__ a, const float* __restrict__ b,
    const float* __restrict__ c, short* __restrict__ out)
{
  const int gid = blockIdx.x * 256 + threadIdx.x;   // 18432 threads, 8 elem each
  const int seg = gid / (WELEM / 8);
  const int off = (gid % (WELEM / 8)) * 8;
  const float* src = (seg == 0) ? a : (seg == 1) ? b : c;
  fx4 v0 = *reinterpret_cast<const fx4*>(src + off);
  fx4 v1 = *reinterpret_cast<const fx4*>(src + off + 4);
  *reinterpret_cast<s16x8*>(out + (size_t)seg * WELEM + off) = cvt8(v0, v1);
}

// ---------------------------------------------------------------------------
// Fused projections. blockIdx.y: 0 -> Q = dec@Wq^T+bq; 1 -> K,V^T from enc.
// Block = 1024 threads = 16 waves = 4 K-groups (K-range 192 each) x 4 waves.
// W is pre-converted bf16 (raw 16B staging loads, no cvt).
// Q-path wave (g, m-subtile): 1 xa + 4 wf reads : 4 MFMA.
// KV-path wave (g, d-quadrant): 2 W reads + 4 xa reads : 8 MFMA (frag reuse).
// Cross-group reduce through Red arrays OVERLAID on dead staging LDS
// (barrier before overlay). LDS = 60 KB union.
// ---------------------------------------------------------------------------
__global__ __launch_bounds__(1024, 4) void proj_fused_kernel(
    const float* __restrict__ dec, const float* __restrict__ enc,
    const short* __restrict__ Wqb, const short* __restrict__ Wkb,
    const short* __restrict__ Wvb,
    const float* __restrict__ bq, const float* __restrict__ bk,
    const float* __restrict__ bv,
    short* __restrict__ Qout, short* __restrict__ Kout,
    short* __restrict__ VT)
{
  __shared__ __align__(16) char smem[61440];
  short (*Xs)[64][40]  = reinterpret_cast<short(*)[64][40]>(smem);          // 20480
  short (*W1s)[64][40] = reinterpret_cast<short(*)[64][40]>(smem + 20480);  // 20480
  short (*W2s)[64][40] = reinterpret_cast<short(*)[64][40]>(smem + 40960);  // 20480
  float (*Red1)[68]    = reinterpret_cast<float(*)[68]>(smem);              // 17408
  float (*Red2)[68]    = reinterpret_cast<float(*)[68]>(smem + 17408);      // 17408

  const int t = threadIdx.x, wv = t >> 6, lane = t & 63;
  const int g = wv >> 2, wl = wv & 3, u = t & 255;
  const int fr = lane & 15, fg = lane >> 4;
  const int m0 = blockIdx.x * 64;
  const int srow = u >> 2, scol = (u & 3) * 8;
  const bool isQ = (blockIdx.y == 0);

  const float* X = isQ ? dec : enc;
  const float* xrow = X + (size_t)(m0 + srow) * EMBED + g * 192 + scol;
  const short* w1row = (isQ ? Wqb : Wkb) + (size_t)srow * EMBED + g * 192 + scol;
  const short* w2row = Wvb + (size_t)srow * EMBED + g * 192 + scol;

  fx4 acc1[4], acc2[4];
#pragma unroll
  for (int i = 0; i < 4; ++i) {
    acc1[i] = fx4{0.f, 0.f, 0.f, 0.f};
    acc2[i] = fx4{0.f, 0.f, 0.f, 0.f};
  }

  fx4 px0 = *reinterpret_cast<const fx4*>(xrow);
  fx4 px1 = *reinterpret_cast<const fx4*>(xrow + 4);
  s16x8 w1 = *reinterpret_cast<const s16x8*>(w1row);
  s16x8 w2;
  if (!isQ) w2 = *reinterpret_cast<const s16x8*>(w2row);

#pragma unroll
  for (int s = 0; s < 6; ++s) {
    s16x8 xb = cvt8(px0, px1);
    __syncthreads();  // previous step's fragment reads complete
    *reinterpret_cast<s16x8*>(&Xs[g][srow][scol])  = xb;
    *reinterpret_cast<s16x8*>(&W1s[g][srow][scol]) = w1;
    if (!isQ) *reinterpret_cast<s16x8*>(&W2s[g][srow][scol]) = w2;
    if (s < 5) {  // register prefetch: hides under ds_write+barrier+compute
      px0 = *reinterpret_cast<const fx4*>(xrow + (s + 1) * 32);
      px1 = *reinterpret_cast<const fx4*>(xrow + (s + 1) * 32 + 4);
      w1  = *reinterpret_cast<const s16x8*>(w1row + (s + 1) * 32);
      if (!isQ) w2 = *reinterpret_cast<const s16x8*>(w2row + (s + 1) * 32);
    }
    __syncthreads();
    if (isQ) {
      // wave (g, m=wl): D[d][m], d = c*16+fg*4+r, m-col = wl*16+fr
      s16x8 xa = *reinterpret_cast<const s16x8*>(&Xs[g][wl * 16 + fr][fg * 8]);
#pragma unroll
      for (int c = 0; c < 4; ++c) {
        s16x8 wf = *reinterpret_cast<const s16x8*>(&W1s[g][c * 16 + fr][fg * 8]);
        acc1[c] = mfma16(wf, xa, acc1[c]);
      }
    } else {
      // wave (g, c=wl): one W-frag pair feeds all 4 m-subtiles
      s16x8 wkf = *reinterpret_cast<const s16x8*>(&W1s[g][wl * 16 + fr][fg * 8]);
      s16x8 wvf = *reinterpret_cast<const s16x8*>(&W2s[g][wl * 16 + fr][fg * 8]);
#pragma unroll
      for (int m = 0; m < 4; ++m) {
        s16x8 xa = *reinterpret_cast<const s16x8*>(&Xs[g][m * 16 + fr][fg * 8]);
        acc1[m] = mfma16(wkf, xa, acc1[m]);
        acc2[m] = mfma16(wvf, xa, acc2[m]);
      }
    }
  }
  __syncthreads();  // staging dead -> safe to overlay Red arrays
  // cross-K-group reduce through LDS (sequential adds)
  for (int gg = 0; gg < 4; ++gg) {
    if (g == gg) {
      if (isQ) {
#pragma unroll
        for (int c = 0; c < 4; ++c) {
          float* p = &Red1[wl * 16 + fr][c * 16 + fg * 4];
          if (gg == 0) {
            *reinterpret_cast<fx4*>(p) = acc1[c];
          } else {
            fx4 v = *reinterpret_cast<fx4*>(p);
#pragma unroll
            for (int r = 0; r < 4; ++r) v[r] += acc1[c][r];
            *reinterpret_cast<fx4*>(p) = v;
          }
        }
      } else {
#pragma unroll
        for (int m = 0; m < 4; ++m) {
          float* pk = &Red1[m * 16 + fr][wl * 16 + fg * 4];
          float* pv = &Red2[m * 16 + fr][wl * 16 + fg * 4];
          if (gg == 0) {
            *reinterpret_cast<fx4*>(pk) = acc1[m];
            *reinterpret_cast<fx4*>(pv) = acc2[m];
          } else {
            fx4 a = *reinterpret_cast<fx4*>(pk);
            fx4 b = *reinterpret_cast<fx4*>(pv);
#pragma unroll
            for (int r = 0; r < 4; ++r) { a[r] += acc1[m][r]; b[r] += acc2[m][r]; }
            *reinterpret_cast<fx4*>(pk) = a;
            *reinterpret_cast<fx4*>(pv) = b;
          }
        }
      }
    }
    __syncthreads();
  }
  // epilogues: 1024 threads, 4 outputs each
  if (isQ) {
    const int row = t >> 4, d0 = (t & 15) * 4;
    fx4 v = *reinterpret_cast<const fx4*>(&Red1[row][d0]);
    fx4 b4 = *reinterpret_cast<const fx4*>(bq + d0);
    *reinterpret_cast<s16x4*>(Qout + (size_t)(m0 + row) * HD + d0) =
        cvt4(v[0] + b4[0], v[1] + b4[1], v[2] + b4[2], v[3] + b4[3]);
  } else {
    {
      const int row = t >> 4, d0 = (t & 15) * 4;
      fx4 v = *reinterpret_cast<const fx4*>(&Red1[row][d0]);
      fx4 b4 = *reinterpret_cast<const fx4*>(bk + d0);
      *reinterpret_cast<s16x4*>(Kout + (size_t)(m0 + row) * HD + d0) =
          cvt4(v[0] + b4[0], v[1] + b4[1], v[2] + b4[2], v[3] + b4[3]);
    }
    {
      const int d = t >> 4, seg = t & 15;
      const int bidx = m0 >> 10;             // 64 | 1024: no batch straddle
      const int kvpos = (m0 & 1023) + seg * 4;
      const float bvd = bv[d];
      *reinterpret_cast<s16x4*>(VT + ((size_t)(bidx * HD + d)) * LEN + kvpos) =
          cvt4(Red2[seg * 4][d] + bvd, Red2[seg * 4 + 1][d] + bvd,
               Red2[seg * 4 + 2][d] + bvd, Red2[seg * 4 + 3][d] + bvd);
    }
  }
}

// ---------------------------------------------------------------------------
// Fused flash attention. 1024 threads = 16 waves = 4 KV-groups x 4 q-waves.
// Wave (g,wl): q rows [wl*16,+16), kv range [g*256,+256). K/V tiles staged in
// LDS per group (shared by its 4 waves), fragments ds_read just before MFMA.
// T14 split: next tile's global loads issue into regs before compute,
// ds_write after the post-compute barrier. Partials combined via LDS overlay.
// ---------------------------------------------------------------------------
__global__ __launch_bounds__(1024, 4) void attn_kernel(
    const short* __restrict__ Q, const short* __restrict__ K,
    const short* __restrict__ VT, float* __restrict__ Out)
{
  __shared__ __align__(16) char smem[110592];
  short (*Kls)[64][72]  = reinterpret_cast<short(*)[64][72]>(smem);
  short (*Vls)[64][72]  = reinterpret_cast<short(*)[64][72]>(smem + 36864);
  short (*Plds)[16][72] = reinterpret_cast<short(*)[16][72]>(smem + 73728);
  float (*HL)[64][68]   = reinterpret_cast<float(*)[64][68]>(smem);
  float2 (*ML)[64]      = reinterpret_cast<float2(*)[64]>(smem + 69632);

  const int t = threadIdx.x, lane = t & 63, w = t >> 6;
  const int g = w >> 2, wl = w & 3;
  const int fr = lane & 15, fg = lane >> 4;
  // XCD-aware mapping (round-robin model: block i -> XCD i&7)
  const int xcd = blockIdx.x & 7;
  const int idx = blockIdx.x >> 3;        // 0..31
  const int b   = xcd + ((idx & 1) << 3);
  const int q0  = (idx >> 1) * 64;
  const int qrow = q0 + wl * 16;

  const short* Qb  = Q  + (size_t)b * LEN * HD;
  const short* Kb  = K  + ((size_t)b * LEN + g * KVQ) * HD;
  const short* VTb = VT + (size_t)b * HD * LEN + g * KVQ;

  s16x8 qa0 = *reinterpret_cast<const s16x8*>(Qb + (size_t)(qrow + fr) * HD + fg * 8);
  s16x8 qa1 = *reinterpret_cast<const s16x8*>(Qb + (size_t)(qrow + fr) * HD + 32 + fg * 8);

  fx4 hacc[4];
#pragma unroll
  for (int c = 0; c < 4; ++c) hacc[c] = fx4{0.f, 0.f, 0.f, 0.f};
  float mrun = -1e30f, lsum = 0.f;
  const float SC = 0.125f * 1.44269504088896340736f;  // 1/sqrt(64) * log2(e)

  const int u = t & 255;
  const int srow = u >> 2;          // 0..63
  const int sch  = (u & 3) * 16;    // short col offset: 0,16,32,48 (32B/lane)

  // prologue: load tile 0 -> regs -> LDS
  s16x8 pk0 = *reinterpret_cast<const s16x8*>(Kb + (size_t)srow * HD + sch);
  s16x8 pk1 = *reinterpret_cast<const s16x8*>(Kb + (size_t)srow * HD + sch + 8);
  s16x8 pv0 = *reinterpret_cast<const s16x8*>(VTb + (size_t)srow * LEN + sch);
  s16x8 pv1 = *reinterpret_cast<const s16x8*>(VTb + (size_t)srow * LEN + sch + 8);
  *reinterpret_cast<s16x8*>(&Kls[g][srow][sch])     = pk0;
  *reinterpret_cast<s16x8*>(&Kls[g][srow][sch + 8]) = pk1;
  *reinterpret_cast<s16x8*>(&Vls[g][srow][sch])     = pv0;
  *reinterpret_cast<s16x8*>(&Vls[g][srow][sch + 8]) = pv1;
  __syncthreads();

#pragma unroll
  for (int it = 0; it < KVQ / 64; ++it) {
    if (it + 1 < KVQ / 64) {  // T14: issue next tile's loads before compute
      const int nk = (it + 1) * 64;
      pk0 = *reinterpret_cast<const s16x8*>(Kb + (size_t)(nk + srow) * HD + sch);
      pk1 = *reinterpret_cast<const s16x8*>(Kb + (size_t)(nk + srow) * HD + sch + 8);
      pv0 = *reinterpret_cast<const s16x8*>(VTb + (size_t)srow * LEN + nk + sch);
      pv1 = *reinterpret_cast<const s16x8*>(VTb + (size_t)srow * LEN + nk + sch + 8);
    }
    fx4 sacc[4];
#pragma unroll
    for (int s = 0; s < 4; ++s) {
      s16x8 kf0 = *reinterpret_cast<const s16x8*>(&Kls[g][s * 16 + fr][fg * 8]);
      s16x8 kf1 = *reinterpret_cast<const s16x8*>(&Kls[g][s * 16 + fr][32 + fg * 8]);
      fx4 z = fx4{0.f, 0.f, 0.f, 0.f};
      z = mfma16(kf0, qa0, z);
      sacc[s] = mfma16(kf1, qa1, z);
    }
    float xs[4][4];
    float xm = -1e30f;
#pragma unroll
    for (int s = 0; s < 4; ++s)
#pragma unroll
      for (int r = 0; r < 4; ++r) {
        xs[s][r] = sacc[s][r] * SC;
        xm = fmaxf(xm, xs[s][r]);
      }
    xm = fmaxf(xm, __shfl_xor(xm, 16, 64));
    xm = fmaxf(xm, __shfl_xor(xm, 32, 64));
    const float mn = fmaxf(mrun, xm);
    const float corr = __builtin_amdgcn_exp2f(mrun - mn);
    mrun = mn;
    float ps = 0.f;
#pragma unroll
    for (int s = 0; s < 4; ++s) {
      float p[4];
#pragma unroll
      for (int r = 0; r < 4; ++r) {
        p[r] = __builtin_amdgcn_exp2f(xs[s][r] - mn);
        ps += p[r];
      }
      *reinterpret_cast<s16x4*>(&Plds[w][fr][s * 16 + fg * 4]) =
          cvt4(p[0], p[1], p[2], p[3]);
    }
    ps += __shfl_xor(ps, 16, 64);
    ps += __shfl_xor(ps, 32, 64);
    lsum = lsum * corr + ps;
    __builtin_amdgcn_wave_barrier();
    s16x8 pa0 = *reinterpret_cast<const s16x8*>(&Plds[w][fr][fg * 8]);
    s16x8 pa1 = *reinterpret_cast<const s16x8*>(&Plds[w][fr][32 + fg * 8]);
#pragma unroll
    for (int c = 0; c < 4; ++c) {
      s16x8 vf0 = *reinterpret_cast<const s16x8*>(&Vls[g][c * 16 + fr][fg * 8]);
      s16x8 vf1 = *reinterpret_cast<const s16x8*>(&Vls[g][c * 16 + fr][32 + fg * 8]);
      fx4 h = hacc[c];
#pragma unroll
      for (int r = 0; r < 4; ++r) h[r] *= corr;
      h = mfma16(vf0, pa0, h);
      hacc[c] = mfma16(vf1, pa1, h);
    }
    __syncthreads();  // all waves done reading tile it
    if (it + 1 < KVQ / 64) {
      *reinterpret_cast<s16x8*>(&Kls[g][srow][sch])     = pk0;
      *reinterpret_cast<s16x8*>(&Kls[g][srow][sch + 8]) = pk1;
      *reinterpret_cast<s16x8*>(&Vls[g][srow][sch])     = pv0;
      *reinterpret_cast<s16x8*>(&Vls[g][srow][sch + 8]) = pv1;
    }
    __syncthreads();  // tile it+1 visible
  }
  // partials -> LDS overlay (staging dead; barrier above done)
#pragma unroll
  for (int c = 0; c < 4; ++c)
    *reinterpret_cast<fx4*>(&HL[g][wl * 16 + fr][c * 16 + fg * 4]) = hacc[c];
  if (fg == 0) ML[g][wl * 16 + fr] = make_float2(mrun, lsum);
  __syncthreads();
  // combine 4 KV-groups per q-row; 1024 threads x 4 outputs
  const int row = t >> 4, d0 = (t & 15) * 4;
  const float2 s0 = ML[0][row], s1 = ML[1][row], s2 = ML[2][row], s3 = ML[3][row];
  const float mm = fmaxf(fmaxf(s0.x, s1.x), fmaxf(s2.x, s3.x));
  const float w0 = __builtin_amdgcn_exp2f(s0.x - mm);
  const float w1 = __builtin_amdgcn_exp2f(s1.x - mm);
  const float w2 = __builtin_amdgcn_exp2f(s2.x - mm);
  const float w3 = __builtin_amdgcn_exp2f(s3.x - mm);
  const float inv = 1.0f / (s0.y * w0 + s1.y * w1 + s2.y * w2 + s3.y * w3);
  fx4 h0 = *reinterpret_cast<const fx4*>(&HL[0][row][d0]);
  fx4 h1 = *reinterpret_cast<const fx4*>(&HL[1][row][d0]);
  fx4 h2 = *reinterpret_cast<const fx4*>(&HL[2][row][d0]);
  fx4 h3 = *reinterpret_cast<const fx4*>(&HL[3][row][d0]);
  fx4 o;
#pragma unroll
  for (int r = 0; r < 4; ++r)
    o[r] = (h0[r] * w0 + h1[r] * w1 + h2[r] * w2 + h3[r] * w3) * inv;
  *reinterpret_cast<fx4*>(Out + ((size_t)b * LEN + q0 + row) * HD + d0) = o;
}

extern "C" void kernel_launch(void* const* d_in, const int* in_sizes, int n_in,
                              void* d_out, int out_size, void* d_ws, size_t ws_size,
                              hipStream_t stream) {
  const float* dec = (const float*)d_in[0];
  const float* enc = (const float*)d_in[1];
  const float* Wq  = (const float*)d_in[2];
  const float* bq  = (const float*)d_in[3];
  const float* Wk  = (const float*)d_in[4];
  const float* bk  = (const float*)d_in[5];
  const float* Wv  = (const float*)d_in[6];
  const float* bv  = (const float*)d_in[7];
  float* out = (float*)d_out;

  short* qws  = (short*)d_ws;                        // [16384,64] bf16
  short* kws  = qws + (size_t)M_TOT * HD;            // [16384,64] bf16
  short* vtws = kws + (size_t)M_TOT * HD;            // [16,64,1024] bf16
  short* wbuf = vtws + (size_t)NB * HD * LEN;        // [3][49152] bf16 weights

  convert_w_kernel<<<(3 * WELEM / 8) / 256, 256, 0, stream>>>(Wq, Wk, Wv, wbuf);
  proj_fused_kernel<<<dim3(M_TOT / 64, 2), 1024, 0, stream>>>(
      dec, enc, wbuf, wbuf + WELEM, wbuf + 2 * (size_t)WELEM,
      bq, bk, bv, qws, kws, vtws);
  attn_kernel<<<NB * (LEN / 64), 1024, 0, stream>>>(qws, kws, vtws, out);
}